// Round 1
// baseline (444.938 us; speedup 1.0000x reference)
//
#include <hip/hip_runtime.h>

// LoKr: out = x @ (W + 2*scalar*(A kron B))^T  with B (16,1)
// => out[m,r] = (x@W^T)[m,r] + 2*scalar*B[r&15] * (x@A^T)[m, r>>4]
// Main GEMM: M=128, N=8192, K=8192, bf16 MFMA, W converted fp32->bf16 on the fly.
// A-rows for each n-tile (8 of them) are appended as a 9th (zero-padded to 16)
// n-subtile so the y2 = x@A^T partial is computed by the same MFMA loop.

#define M_DIM 128
#define N_DIM 8192
#define K_DIM 8192
#define BN 128
#define BK 64
#define KSPLIT 8
#define KCHUNK (K_DIM / KSPLIT)   // 1024

typedef __attribute__((ext_vector_type(8))) short bf16x8;   // 8 bf16 = 4 VGPRs
typedef __attribute__((ext_vector_type(4))) float f32x4;    // MFMA acc

__device__ __forceinline__ unsigned short f2bf(float f) {
  // round-to-nearest-even fp32 -> bf16 (inputs are finite randn; no NaN path)
  unsigned u = __builtin_bit_cast(unsigned, f);
  u += 0x7FFFu + ((u >> 16) & 1u);
  return (unsigned short)(u >> 16);
}

__global__ void convert_x_kernel(const float4* __restrict__ x4,
                                 ushort4* __restrict__ xb4) {
  int t = blockIdx.x * blockDim.x + threadIdx.x;
  const int n4 = M_DIM * K_DIM / 4;  // 262144
  for (int i = t; i < n4; i += gridDim.x * blockDim.x) {
    float4 v = x4[i];
    ushort4 o;
    o.x = f2bf(v.x); o.y = f2bf(v.y); o.z = f2bf(v.z); o.w = f2bf(v.w);
    xb4[i] = o;
  }
}

__global__ __launch_bounds__(256, 2) void lokr_main(
    const float* __restrict__ W,          // 8192 x 8192
    const float* __restrict__ A,          // 512 x 8192
    const float* __restrict__ Bv,         // 16
    const float* __restrict__ scal,       // 1
    const unsigned short* __restrict__ xb,// x as bf16, 128 x 8192
    float* __restrict__ part)             // [KSPLIT][128][8192] fp32 partials
{
  __shared__ unsigned short xs[M_DIM][BK];   // 16 KiB, layout required by global_load_lds
  __shared__ unsigned short bs[BN + 16][BK]; // 18 KiB: W rows 0..127, A rows 128..143

  const int t    = threadIdx.x;
  const int lane = t & 63;
  const int wv   = t >> 6;                 // wave 0..3, owns m rows [32*wv, 32*wv+32)
  const int bx   = blockIdx.x;
  const int ks   = bx & (KSPLIT - 1);      // bx%8: same-XCD blocks share the same x K-chunk
  const int ntb  = bx >> 3;                // n-tile 0..63
  const int r0   = ntb * BN;
  const int i0   = ntb * (BN / 16);        // first A-row for this tile (8 per tile)
  const int kbase = ks * KCHUNK;

  const float sB = 2.0f * scal[0] * Bv[lane & 15];  // 2*scalar*B[r&15], r&15 == lane&15

  f32x4 accW[2][8];
  f32x4 accY[2];
  const f32x4 z4 = {0.f, 0.f, 0.f, 0.f};
#pragma unroll
  for (int a = 0; a < 2; ++a) {
    accY[a] = z4;
#pragma unroll
    for (int b = 0; b < 8; ++b) accW[a][b] = z4;
  }

  for (int kt = 0; kt < KCHUNK; kt += BK) {
    const int k0 = kbase + kt;
    __syncthreads();
    // --- stage W tile 128x64 fp32 -> bf16 LDS (VALU convert pass) ---
#pragma unroll
    for (int j = 0; j < 8; ++j) {
      int c = j * 256 + t;         // 2048 16B-chunks
      int row = c >> 4, cc = c & 15;
      float4 v = *(const float4*)(W + (size_t)(r0 + row) * K_DIM + k0 + cc * 4);
      ushort4 o;
      o.x = f2bf(v.x); o.y = f2bf(v.y); o.z = f2bf(v.z); o.w = f2bf(v.w);
      *(ushort4*)&bs[row][cc * 4] = o;
    }
    // --- stage 8 A rows (+8 zero pad rows) ---
    {
      int row = t >> 4, cc = t & 15;       // 16 rows x 16 chunks = 256 threads
      ushort4 o;
      if (row < 8) {
        float4 v = *(const float4*)(A + (size_t)(i0 + row) * K_DIM + k0 + cc * 4);
        o.x = f2bf(v.x); o.y = f2bf(v.y); o.z = f2bf(v.z); o.w = f2bf(v.w);
      } else {
        o.x = o.y = o.z = o.w = 0;
      }
      *(ushort4*)&bs[BN + row][cc * 4] = o;
    }
    // --- stage x tile 128x64 bf16 via async global->LDS, 16B/lane ---
#pragma unroll
    for (int j = 0; j < 4; ++j) {
      int c = j * 256 + t;                 // 1024 16B-chunks; LDS addr == c*16 (contiguous)
      int row = c >> 3, cc = c & 7;
      const unsigned short* g = xb + (size_t)row * K_DIM + k0 + cc * 8;
      __builtin_amdgcn_global_load_lds(
          (const __attribute__((address_space(1))) unsigned int*)g,
          (__attribute__((address_space(3))) unsigned int*)
              ((char*)&xs[0][0] + (size_t)(j * 256 + wv * 64) * 16),
          16, 0, 0);
    }
    __syncthreads();
    // --- MFMA: 2 k-steps x 2 m-tiles x (8 W n-tiles + 1 A n-tile) ---
#pragma unroll
    for (int kk = 0; kk < 2; ++kk) {
      const int koff = kk * 32 + (lane >> 4) * 8;
      bf16x8 af[2];
#pragma unroll
      for (int mt = 0; mt < 2; ++mt)
        af[mt] = *(const bf16x8*)&xs[wv * 32 + mt * 16 + (lane & 15)][koff];
#pragma unroll
      for (int n9 = 0; n9 < 9; ++n9) {
        bf16x8 bf = *(const bf16x8*)&bs[n9 * 16 + (lane & 15)][koff];
#pragma unroll
        for (int mt = 0; mt < 2; ++mt) {
          if (n9 < 8)
            accW[mt][n9] = __builtin_amdgcn_mfma_f32_16x16x32_bf16(af[mt], bf, accW[mt][n9], 0, 0, 0);
          else
            accY[mt] = __builtin_amdgcn_mfma_f32_16x16x32_bf16(af[mt], bf, accY[mt], 0, 0, 0);
        }
      }
    }
  }

  // --- epilogue: partial = accW + sB * y2partial; y2[m, i=nt] lives in lane (lane&48)|nt ---
  float* p = part + (size_t)ks * M_DIM * N_DIM;
#pragma unroll
  for (int mt = 0; mt < 2; ++mt) {
#pragma unroll
    for (int n9 = 0; n9 < 8; ++n9) {
      int srcl = (lane & 48) | n9;
#pragma unroll
      for (int reg = 0; reg < 4; ++reg) {
        float y2v = __shfl(accY[mt][reg], srcl, 64);
        int m = wv * 32 + mt * 16 + (lane >> 4) * 4 + reg;   // C-layout row
        int r = r0 + n9 * 16 + (lane & 15);                  // C-layout col
        p[(size_t)m * N_DIM + r] = accW[mt][n9][reg] + sB * y2v;
      }
    }
  }
}

__global__ void reduce_kernel(const float4* __restrict__ part,
                              float4* __restrict__ out) {
  int t = blockIdx.x * blockDim.x + threadIdx.x;
  const int n4 = M_DIM * N_DIM / 4;  // 262144
  for (int i = t; i < n4; i += gridDim.x * blockDim.x) {
    float4 s = part[i];
#pragma unroll
    for (int ksp = 1; ksp < KSPLIT; ++ksp) {
      float4 v = part[(size_t)ksp * n4 + i];
      s.x += v.x; s.y += v.y; s.z += v.z; s.w += v.w;
    }
    out[i] = s;
  }
}

extern "C" void kernel_launch(void* const* d_in, const int* in_sizes, int n_in,
                              void* d_out, int out_size, void* d_ws, size_t ws_size,
                              hipStream_t stream) {
  const float* x    = (const float*)d_in[0];   // 128 x 8192
  const float* W    = (const float*)d_in[1];   // 8192 x 8192
  const float* A    = (const float*)d_in[2];   // 512 x 8192
  const float* Bv   = (const float*)d_in[3];   // 16
  const float* scal = (const float*)d_in[4];   // 1
  float* out = (float*)d_out;

  // ws layout: [0, 2MB) x as bf16; [2MB, 2MB+32MB) fp32 partials [KSPLIT][128][8192]
  unsigned short* xb = (unsigned short*)d_ws;
  float* part = (float*)((char*)d_ws + (size_t)M_DIM * K_DIM * sizeof(unsigned short));

  convert_x_kernel<<<256, 256, 0, stream>>>((const float4*)x, (ushort4*)xb);
  lokr_main<<<(N_DIM / BN) * KSPLIT, 256, 0, stream>>>(W, A, Bv, scal, xb, part);
  reduce_kernel<<<512, 256, 0, stream>>>((const float4*)part, (float4*)out);
}

// Round 2
// 414.417 us; speedup vs baseline: 1.0736x; 1.0736x over previous
//
#include <hip/hip_runtime.h>

// LoKr: out = x @ (W + 2*scalar*(A kron B))^T  with B (16,1)
// => out[m,r] = (x@W^T)[m,r] + 2*scalar*B[r&15] * (x@A^T)[m, r>>4]
// Main GEMM: M=128, N=8192, K=8192, bf16 MFMA, W converted fp32->bf16 on the fly.
// A-rows for each n-tile (8 of them) are appended as a 9th (zero-padded to 16)
// n-subtile so y2 = x@A^T partials come from the same MFMA loop.
//
// R2: register-staged software pipeline (prefetch k+1 W/A into VGPRs during
// MFMA of k), padded LDS (row stride 144B -> conflict-free b128 reads),
// x fragments read directly from global (L2-resident bf16 copy) - no xs LDS.

#define M_DIM 128
#define N_DIM 8192
#define K_DIM 8192
#define BN 128
#define BK 64
#define KSPLIT 8
#define KCHUNK (K_DIM / KSPLIT)   // 1024

typedef __attribute__((ext_vector_type(8))) short bf16x8;   // 8 bf16 = 4 VGPRs
typedef __attribute__((ext_vector_type(4))) float f32x4;    // MFMA acc

__device__ __forceinline__ unsigned short f2bf(float f) {
  unsigned u = __builtin_bit_cast(unsigned, f);
  u += 0x7FFFu + ((u >> 16) & 1u);
  return (unsigned short)(u >> 16);
}

__global__ void convert_x_kernel(const float4* __restrict__ x4,
                                 ushort4* __restrict__ xb4) {
  int t = blockIdx.x * blockDim.x + threadIdx.x;
  const int n4 = M_DIM * K_DIM / 4;  // 262144
  for (int i = t; i < n4; i += gridDim.x * blockDim.x) {
    float4 v = x4[i];
    ushort4 o;
    o.x = f2bf(v.x); o.y = f2bf(v.y); o.z = f2bf(v.z); o.w = f2bf(v.w);
    xb4[i] = o;
  }
}

__global__ __launch_bounds__(256, 2) void lokr_main(
    const float* __restrict__ W,          // 8192 x 8192
    const float* __restrict__ A,          // 512 x 8192
    const float* __restrict__ Bv,         // 16
    const float* __restrict__ scal,       // 1
    const unsigned short* __restrict__ xb,// x as bf16, 128 x 8192
    float* __restrict__ part)             // [KSPLIT][128][8192] fp32 partials
{
  // rows 0..127: W tile (bf16); rows 128..135: A rows; 136..143: zeros.
  // row stride 72 ushorts = 144 B = 36 banks -> 4-bank rotation per row,
  // uniform bank load for the 16-lane b128 fragment reads (conflict-free).
  __shared__ unsigned short bs[144][BK + 8];

  const int t    = threadIdx.x;
  const int lane = t & 63;
  const int wv   = t >> 6;                 // wave 0..3, owns m rows [32*wv, 32*wv+32)
  const int bx   = blockIdx.x;
  const int ks   = bx & (KSPLIT - 1);      // same-XCD blocks share the same x K-chunk
  const int ntb  = bx >> 3;                // n-tile 0..63
  const int r0   = ntb * BN;
  const int i0   = ntb * (BN / 16);        // first A-row for this tile (8 per tile)
  const int kbase = ks * KCHUNK;
  const int tr = t >> 4, tc = t & 15;      // staging row-within-16 / 16B-chunk

  const float sB = 2.0f * scal[0] * Bv[lane & 15];

  f32x4 accW[2][8];
  f32x4 accY[2];
  const f32x4 z4 = {0.f, 0.f, 0.f, 0.f};
#pragma unroll
  for (int a = 0; a < 2; ++a) {
    accY[a] = z4;
#pragma unroll
    for (int b = 0; b < 8; ++b) accW[a][b] = z4;
  }

  // staging base pointers (thread-invariant part of address precomputed)
  const float* Wrow = W + (size_t)(r0 + tr) * K_DIM + kbase + tc * 4;
  const float* Arow = A + (size_t)(i0 + (tr & 7)) * K_DIM + kbase + tc * 4;
  const bool aact = (tr < 8);
  const unsigned short* xcol = xb + kbase;

  // ---- prologue: load tile 0 into registers ----
  float4 wreg[8];
  float4 areg;
#pragma unroll
  for (int j = 0; j < 8; ++j)
    wreg[j] = *(const float4*)(Wrow + (size_t)j * 16 * K_DIM);
  if (aact) areg = *(const float4*)Arow;
  else      { areg.x = areg.y = areg.z = areg.w = 0.f; }

  for (int kt = 0; kt < KCHUNK; kt += BK) {
    // ---- convert current regs -> LDS ----
#pragma unroll
    for (int j = 0; j < 8; ++j) {
      ushort4 o;
      o.x = f2bf(wreg[j].x); o.y = f2bf(wreg[j].y);
      o.z = f2bf(wreg[j].z); o.w = f2bf(wreg[j].w);
      *(ushort4*)&bs[j * 16 + tr][tc * 4] = o;
    }
    {
      ushort4 o;
      o.x = f2bf(areg.x); o.y = f2bf(areg.y);
      o.z = f2bf(areg.z); o.w = f2bf(areg.w);
      *(ushort4*)&bs[128 + tr][tc * 4] = o;
    }
    __syncthreads();

    // ---- issue next tile's loads (wait deferred to next iteration) ----
    if (kt + BK < KCHUNK) {
#pragma unroll
      for (int j = 0; j < 8; ++j)
        wreg[j] = *(const float4*)(Wrow + (size_t)j * 16 * K_DIM + kt + BK);
      if (aact) areg = *(const float4*)(Arow + kt + BK);
    }

    // ---- MFMA phase: x frags from global (L2), W/A frags from LDS ----
    bf16x8 af[2][2];
#pragma unroll
    for (int kk = 0; kk < 2; ++kk) {
      const int koff = kk * 32 + (lane >> 4) * 8;
#pragma unroll
      for (int mt = 0; mt < 2; ++mt)
        af[kk][mt] = *(const bf16x8*)(xcol +
            (size_t)(wv * 32 + mt * 16 + (lane & 15)) * K_DIM + kt + koff);
    }
#pragma unroll
    for (int kk = 0; kk < 2; ++kk) {
      const int koff = kk * 32 + (lane >> 4) * 8;
#pragma unroll
      for (int n9 = 0; n9 < 9; ++n9) {
        bf16x8 bf = *(const bf16x8*)&bs[n9 * 16 + (lane & 15)][koff];
#pragma unroll
        for (int mt = 0; mt < 2; ++mt) {
          if (n9 < 8)
            accW[mt][n9] = __builtin_amdgcn_mfma_f32_16x16x32_bf16(af[kk][mt], bf, accW[mt][n9], 0, 0, 0);
          else
            accY[mt] = __builtin_amdgcn_mfma_f32_16x16x32_bf16(af[kk][mt], bf, accY[mt], 0, 0, 0);
        }
      }
    }
    __syncthreads();
  }

  // ---- epilogue: partial = accW + sB * y2partial ----
  // y2[m, i=nt] lives in lane (lane&48)|nt of accY (C-layout col = src lane&15)
  float* p = part + (size_t)ks * M_DIM * N_DIM;
#pragma unroll
  for (int mt = 0; mt < 2; ++mt) {
#pragma unroll
    for (int n9 = 0; n9 < 8; ++n9) {
      int srcl = (lane & 48) | n9;
#pragma unroll
      for (int reg = 0; reg < 4; ++reg) {
        float y2v = __shfl(accY[mt][reg], srcl, 64);
        int m = wv * 32 + mt * 16 + (lane >> 4) * 4 + reg;   // C-layout row
        int r = r0 + n9 * 16 + (lane & 15);                  // C-layout col
        p[(size_t)m * N_DIM + r] = accW[mt][n9][reg] + sB * y2v;
      }
    }
  }
}

__global__ void reduce_kernel(const float4* __restrict__ part,
                              float4* __restrict__ out) {
  int t = blockIdx.x * blockDim.x + threadIdx.x;
  const int n4 = M_DIM * N_DIM / 4;  // 262144
  for (int i = t; i < n4; i += gridDim.x * blockDim.x) {
    float4 s = part[i];
#pragma unroll
    for (int ksp = 1; ksp < KSPLIT; ++ksp) {
      float4 v = part[(size_t)ksp * n4 + i];
      s.x += v.x; s.y += v.y; s.z += v.z; s.w += v.w;
    }
    out[i] = s;
  }
}

extern "C" void kernel_launch(void* const* d_in, const int* in_sizes, int n_in,
                              void* d_out, int out_size, void* d_ws, size_t ws_size,
                              hipStream_t stream) {
  const float* x    = (const float*)d_in[0];   // 128 x 8192
  const float* W    = (const float*)d_in[1];   // 8192 x 8192
  const float* A    = (const float*)d_in[2];   // 512 x 8192
  const float* Bv   = (const float*)d_in[3];   // 16
  const float* scal = (const float*)d_in[4];   // 1
  float* out = (float*)d_out;

  // ws layout: [0, 2MB) x as bf16; [2MB, 2MB+32MB) fp32 partials [KSPLIT][128][8192]
  unsigned short* xb = (unsigned short*)d_ws;
  float* part = (float*)((char*)d_ws + (size_t)M_DIM * K_DIM * sizeof(unsigned short));

  convert_x_kernel<<<512, 256, 0, stream>>>((const float4*)x, (ushort4*)xb);
  lokr_main<<<(N_DIM / BN) * KSPLIT, 256, 0, stream>>>(W, A, Bv, scal, xb, part);
  reduce_kernel<<<1024, 256, 0, stream>>>((const float4*)part, (float4*)out);
}